// Round 7
// baseline (185.546 us; speedup 1.0000x reference)
//
#include <hip/hip_runtime.h>

#define MROWS   16384
#define NCOLS   256
#define NV2     (NCOLS / 2)        // 128 float2 per row
#define CHUNKS  8                  // column chunks: col>>11 -> 2048 rows = 2 MB each
#define CSHIFT  11
#define NB      (MROWS * CHUNKS)   // 131072 buckets

// chunk-major key: all rows of one chunk contiguous in pack
__device__ __forceinline__ int mk_key(int r, int c) {
    return ((c >> CSHIFT) << 14) | r;
}

// 1024 blocks x 512 threads (8 waves). Waves pair up: pair k owns 4 rows,
// wave (2k) takes cols 0..127, wave (2k+1) takes cols 128..255 (float2/lane).
// Per-wave phase quantum stays ~32 items (R3's proven lockstep granularity)
// while occupancy doubles to 32 waves/CU.
#define SPMM_BLOCKS 1024
#define RPB 16                                 // rows per block
#define RPP 4                                  // rows per wave-pair

#define SCAT_BLOCKS 2048

// ---------------- K2: histogram of chunk-major keys (int4 loads) ----------------
__global__ void k_hist(const int* __restrict__ rows, const int* __restrict__ cols,
                       int* __restrict__ cnt, int nnz) {
    int t = blockIdx.x * blockDim.x + threadIdx.x;
    int i = t * 4;
    if (i + 3 < nnz) {
        int4 r = *(const int4*)(rows + i);
        int4 c = *(const int4*)(cols + i);
        atomicAdd(&cnt[mk_key(r.x, c.x)], 1);
        atomicAdd(&cnt[mk_key(r.y, c.y)], 1);
        atomicAdd(&cnt[mk_key(r.z, c.z)], 1);
        atomicAdd(&cnt[mk_key(r.w, c.w)], 1);
    } else {
        for (int j = i; j < nnz; ++j)
            atomicAdd(&cnt[mk_key(rows[j], cols[j])], 1);
    }
}

// ---------------- scan stage 1: coalesced per-block sums (512 x 256) ----------------
__global__ __launch_bounds__(256) void k_scan1(const int* __restrict__ cnt,
                                               int* __restrict__ bsum) {
    __shared__ int sm[256];
    const int t = threadIdx.x;
    sm[t] = cnt[blockIdx.x * 256 + t];
    __syncthreads();
    for (int off = 128; off > 0; off >>= 1) {
        if (t < off) sm[t] += sm[t + off];
        __syncthreads();
    }
    if (t == 0) bsum[blockIdx.x] = sm[0];
}

// ---------------- scan stage 2: 1 block scans the 512 block sums ----------------
__global__ __launch_bounds__(512) void k_scan2(const int* __restrict__ bsum,
                                               int* __restrict__ bpre) {
    __shared__ int sm[512];
    const int t = threadIdx.x;
    int v = bsum[t];
    sm[t] = v;
    __syncthreads();
    for (int off = 1; off < 512; off <<= 1) {
        int u = 0;
        if (t >= off) u = sm[t - off];
        __syncthreads();
        if (t >= off) sm[t] += u;
        __syncthreads();
    }
    bpre[t] = sm[t] - v;                 // exclusive
    if (t == 511) bpre[512] = sm[511];   // total
}

// ---------------- scan stage 3: coalesced final exclusive prefix ----------------
__global__ __launch_bounds__(256) void k_scan3(const int* __restrict__ cnt_in,
                                               const int* __restrict__ bpre,
                                               int* __restrict__ bstart,
                                               int* __restrict__ cursor) {
    __shared__ int sm[256];
    const int t = threadIdx.x;
    const int g = blockIdx.x * 256 + t;
    int v = cnt_in[g];
    sm[t] = v;
    __syncthreads();
    for (int off = 1; off < 256; off <<= 1) {
        int u = 0;
        if (t >= off) u = sm[t - off];
        __syncthreads();
        if (t >= off) sm[t] += u;
        __syncthreads();
    }
    int excl = sm[t] - v + bpre[blockIdx.x];
    bstart[g] = excl;
    cursor[g] = excl;
    if (blockIdx.x == gridDim.x - 1 && t == 255) bstart[NB] = bpre[512];
}

// ---------------- K4: XCD-filtered scatter ----------------
__global__ __launch_bounds__(256) void k_scatter(const float* __restrict__ values,
                                                 const int* __restrict__ rows,
                                                 const int* __restrict__ cols,
                                                 int* __restrict__ cursor,
                                                 int2* __restrict__ pack, int nnz) {
    const int f      = blockIdx.x & 7;          // chunk filter
    const int slice  = blockIdx.x >> 3;         // 256 slices
    const int nslice = SCAT_BLOCKS / 8;
    const int per    = (nnz + nslice - 1) / nslice;
    const int begin  = slice * per;
    const int end    = min(begin + per, nnz);
    for (int i = begin + threadIdx.x; i < end; i += 256) {
        int c = cols[i];
        if ((c >> CSHIFT) == f) {
            int r   = rows[i];
            int pos = atomicAdd(&cursor[mk_key(r, c)], 1);
            pack[pos] = make_int2(c, __float_as_int(values[i]));
        }
    }
}

// ---------------- K5: chunk-phased gather-accumulate, column-split waves ----------------
__global__ __launch_bounds__(512, 8) void k_spmm(const float2* __restrict__ in2,
                                                 const int2* __restrict__ pack,
                                                 const int* __restrict__ bstart,
                                                 const float2* __restrict__ dense2,
                                                 float2* __restrict__ out2) {
    const int wave  = threadIdx.x >> 6;          // 0..7
    const int lane  = threadIdx.x & 63;
    const int pairi = wave >> 1;                 // 0..3
    const int half  = wave & 1;                  // column half
    const int rb    = blockIdx.x * RPB + pairi * RPP;   // rows rb..rb+3
    const int cb    = half * 64 + lane;          // float2 index within row (0..127)
    const int ph0   = blockIdx.x & 7;

    float2 a[RPP];
#pragma unroll
    for (int r = 0; r < RPP; ++r) a[r] = make_float2(0.f, 0.f);

    for (int p = 0; p < CHUNKS; ++p) {
        const int ch   = (ph0 + p) & 7;
        const int base = ch * MROWS + rb;
#pragma unroll
        for (int r = 0; r < RPP; ++r) {
            int s = bstart[base + r];
            int e = bstart[base + r + 1];
            s = __builtin_amdgcn_readfirstlane(s);
            e = __builtin_amdgcn_readfirstlane(e);
            int i = s;
            for (; i + 4 <= e; i += 4) {
                int2 q0 = pack[i + 0], q1 = pack[i + 1];
                int2 q2 = pack[i + 2], q3 = pack[i + 3];
                float2 d0 = dense2[q0.x * NV2 + cb];
                float2 d1 = dense2[q1.x * NV2 + cb];
                float2 d2 = dense2[q2.x * NV2 + cb];
                float2 d3 = dense2[q3.x * NV2 + cb];
                float v0 = __int_as_float(q0.y), v1 = __int_as_float(q1.y);
                float v2 = __int_as_float(q2.y), v3 = __int_as_float(q3.y);
                a[r].x += v0 * d0.x; a[r].y += v0 * d0.y;
                a[r].x += v1 * d1.x; a[r].y += v1 * d1.y;
                a[r].x += v2 * d2.x; a[r].y += v2 * d2.y;
                a[r].x += v3 * d3.x; a[r].y += v3 * d3.y;
            }
            for (; i < e; ++i) {
                int2 q   = pack[i];
                float2 d = dense2[q.x * NV2 + cb];
                float v  = __int_as_float(q.y);
                a[r].x += v * d.x; a[r].y += v * d.y;
            }
        }
        __syncthreads();   // re-align the block's 8 waves at each phase boundary
    }

#pragma unroll
    for (int r = 0; r < RPP; ++r) {
        const int o = (rb + r) * NV2 + cb;
        float2 iv = in2[o];
        out2[o] = make_float2(iv.x + a[r].x, iv.y + a[r].y);
    }
}

// ---------------- Fallback path (if ws too small): copy + atomic scatter ----------------
__global__ void k_copy4(const float4* __restrict__ in4, float4* __restrict__ out4, int n4) {
    int t = blockIdx.x * blockDim.x + threadIdx.x;
    if (t < n4) out4[t] = in4[t];
}

__global__ void k_atomic(const float* __restrict__ values, const int* __restrict__ rows,
                         const int* __restrict__ cols, const float4* __restrict__ dense4,
                         float* __restrict__ out, int nnz) {
    long long t = (long long)blockIdx.x * blockDim.x + threadIdx.x;
    long long total = (long long)nnz * 64;
    if (t >= total) return;
    int i   = (int)(t >> 6);
    int seg = (int)(t & 63);
    float v  = values[i];
    float4 d = dense4[cols[i] * (NCOLS / 4) + seg];
    float* o = out + (size_t)rows[i] * NCOLS + seg * 4;
    atomicAdd(o + 0, v * d.x);
    atomicAdd(o + 1, v * d.y);
    atomicAdd(o + 2, v * d.z);
    atomicAdd(o + 3, v * d.w);
}

extern "C" void kernel_launch(void* const* d_in, const int* in_sizes, int n_in,
                              void* d_out, int out_size, void* d_ws, size_t ws_size,
                              hipStream_t stream) {
    const float* input_mat = (const float*)d_in[0];
    const float* values    = (const float*)d_in[1];
    const int*   rows      = (const int*)d_in[2];
    const int*   cols      = (const int*)d_in[3];
    const float* dense     = (const float*)d_in[4];
    float*       out       = (float*)d_out;

    const int nnz = in_sizes[1];

    // ws layout: cursor[NB] | bstart[NB+1] | bsum[512] | bpre[513] | pack[nnz] int2
    const size_t off_cursor = 0;
    const size_t off_bs     = (size_t)NB * 4;
    const size_t off_bsum   = off_bs + ((size_t)NB + 1) * 4;
    const size_t off_bpre   = off_bsum + 512 * 4;
    size_t off_pack         = off_bpre + 513 * 4;
    off_pack                = (off_pack + 255) & ~(size_t)255;
    const size_t need       = off_pack + (size_t)nnz * 8;

    char* ws = (char*)d_ws;

    if (ws_size >= need) {
        int*  cursor = (int*)(ws + off_cursor);
        int*  bstart = (int*)(ws + off_bs);
        int*  bsum   = (int*)(ws + off_bsum);
        int*  bpre   = (int*)(ws + off_bpre);
        int2* pack   = (int2*)(ws + off_pack);

        hipMemsetAsync(cursor, 0, (size_t)NB * 4, stream);
        int histThreads = (nnz + 3) / 4;
        k_hist<<<(histThreads + 255) / 256, 256, 0, stream>>>(rows, cols, cursor, nnz);
        k_scan1<<<NB / 256, 256, 0, stream>>>(cursor, bsum);
        k_scan2<<<1, 512, 0, stream>>>(bsum, bpre);
        k_scan3<<<NB / 256, 256, 0, stream>>>(cursor, bpre, bstart, cursor);
        k_scatter<<<SCAT_BLOCKS, 256, 0, stream>>>(values, rows, cols, cursor,
                                                   pack, nnz);
        k_spmm<<<SPMM_BLOCKS, 512, 0, stream>>>((const float2*)input_mat, pack, bstart,
                                                (const float2*)dense, (float2*)out);
    } else {
        // fallback: atomic scatter (slow but needs no scratch)
        const int n4 = MROWS * (NCOLS / 4);
        k_copy4<<<(n4 + 255) / 256, 256, 0, stream>>>((const float4*)input_mat,
                                                      (float4*)out, n4);
        long long total = (long long)nnz * 64;
        int blocks = (int)((total + 255) / 256);
        k_atomic<<<blocks, 256, 0, stream>>>(values, rows, cols, (const float4*)dense,
                                             out, nnz);
    }
}

// Round 8
// 166.287 us; speedup vs baseline: 1.1158x; 1.1158x over previous
//
#include <hip/hip_runtime.h>

#define MROWS   16384
#define NCOLS   256
#define NV4     (NCOLS / 4)        // 64 float4 per row
#define CHUNKS  8                  // column chunks: col>>11 -> 2048 rows = 2 MB each
#define CSHIFT  11
#define NB      (MROWS * CHUNKS)   // 131072 buckets

// chunk-major key: all rows of one chunk contiguous in pack
__device__ __forceinline__ int mk_key(int r, int c) {
    return ((c >> CSHIFT) << 14) | r;
}

// R3's proven spmm decomposition: 1024 blocks x 256 thr, 4 rows/wave,
// ~32 items per wave per chunk-phase (the lockstep-preserving quantum),
// float4 gathers (max bytes per memory instruction).
#define SPMM_BLOCKS 1024
#define RPB 16                                 // rows per block
#define RPW 4                                  // rows per wave

#define SCAT_BLOCKS 2048

// ---------------- K1: fused stage-write + histogram ----------------
// One coalesced pass: stage[i] = {(row<<14)|col, val_bits} (input order, no
// position atomics), plus per-(chunk,row) count atomics.
__global__ __launch_bounds__(256) void k_fuse(const int* __restrict__ rows,
                                              const int* __restrict__ cols,
                                              const float* __restrict__ vals,
                                              int* __restrict__ cnt,
                                              int2* __restrict__ stage, int nnz) {
    int t = blockIdx.x * blockDim.x + threadIdx.x;
    int i = t * 4;
    if (i + 3 < nnz) {
        int4   r = *(const int4*)(rows + i);
        int4   c = *(const int4*)(cols + i);
        float4 v = *(const float4*)(vals + i);
        stage[i + 0] = make_int2((r.x << 14) | c.x, __float_as_int(v.x));
        stage[i + 1] = make_int2((r.y << 14) | c.y, __float_as_int(v.y));
        stage[i + 2] = make_int2((r.z << 14) | c.z, __float_as_int(v.z));
        stage[i + 3] = make_int2((r.w << 14) | c.w, __float_as_int(v.w));
        atomicAdd(&cnt[mk_key(r.x, c.x)], 1);
        atomicAdd(&cnt[mk_key(r.y, c.y)], 1);
        atomicAdd(&cnt[mk_key(r.z, c.z)], 1);
        atomicAdd(&cnt[mk_key(r.w, c.w)], 1);
    } else {
        for (int j = i; j < nnz; ++j) {
            int r = rows[j], c = cols[j];
            stage[j] = make_int2((r << 14) | c, __float_as_int(vals[j]));
            atomicAdd(&cnt[mk_key(r, c)], 1);
        }
    }
}

// ---------------- scan stage 1: coalesced per-block sums (512 x 256) ----------------
__global__ __launch_bounds__(256) void k_scan1(const int* __restrict__ cnt,
                                               int* __restrict__ bsum) {
    __shared__ int sm[256];
    const int t = threadIdx.x;
    sm[t] = cnt[blockIdx.x * 256 + t];
    __syncthreads();
    for (int off = 128; off > 0; off >>= 1) {
        if (t < off) sm[t] += sm[t + off];
        __syncthreads();
    }
    if (t == 0) bsum[blockIdx.x] = sm[0];
}

// ---------------- scan stage 2: 1 block scans the 512 block sums ----------------
__global__ __launch_bounds__(512) void k_scan2(const int* __restrict__ bsum,
                                               int* __restrict__ bpre) {
    __shared__ int sm[512];
    const int t = threadIdx.x;
    int v = bsum[t];
    sm[t] = v;
    __syncthreads();
    for (int off = 1; off < 512; off <<= 1) {
        int u = 0;
        if (t >= off) u = sm[t - off];
        __syncthreads();
        if (t >= off) sm[t] += u;
        __syncthreads();
    }
    bpre[t] = sm[t] - v;                 // exclusive
    if (t == 511) bpre[512] = sm[511];   // total
}

// ---------------- scan stage 3: coalesced final exclusive prefix ----------------
__global__ __launch_bounds__(256) void k_scan3(const int* __restrict__ cnt_in,
                                               const int* __restrict__ bpre,
                                               int* __restrict__ bstart,
                                               int* __restrict__ cursor) {
    __shared__ int sm[256];
    const int t = threadIdx.x;
    const int g = blockIdx.x * 256 + t;
    int v = cnt_in[g];
    sm[t] = v;
    __syncthreads();
    for (int off = 1; off < 256; off <<= 1) {
        int u = 0;
        if (t >= off) u = sm[t - off];
        __syncthreads();
        if (t >= off) sm[t] += u;
        __syncthreads();
    }
    int excl = sm[t] - v + bpre[blockIdx.x];
    bstart[g] = excl;
    cursor[g] = excl;
    if (blockIdx.x == gridDim.x - 1 && t == 255) bstart[NB] = bpre[512];
}

// ---------------- K4: XCD-filtered scatter over the fused stage ----------------
// Reads only stage (coalesced streams, L3-resident after the first filter
// pass); writes stay within one chunk's ~1 MB pack region per XCD.
__global__ __launch_bounds__(256) void k_scat(const int2* __restrict__ stage,
                                              int* __restrict__ cursor,
                                              int2* __restrict__ pack, int nnz) {
    const int f      = blockIdx.x & 7;          // chunk filter
    const int slice  = blockIdx.x >> 3;         // 256 slices
    const int nslice = SCAT_BLOCKS / 8;
    const int per    = (nnz + nslice - 1) / nslice;
    const int begin  = slice * per;
    const int end    = min(begin + per, nnz);
    for (int i = begin + threadIdx.x; i < end; i += 256) {
        int2 it  = stage[i];
        int  col = it.x & 16383;
        if ((col >> CSHIFT) == f) {
            int row = it.x >> 14;
            int pos = atomicAdd(&cursor[(f << 14) | row], 1);
            pack[pos] = make_int2(col, it.y);
        }
    }
}

// ---------------- K4b: raw-array scatter (mid-tier ws fallback) ----------------
__global__ __launch_bounds__(256) void k_scat_raw(const float* __restrict__ values,
                                                  const int* __restrict__ rows,
                                                  const int* __restrict__ cols,
                                                  int* __restrict__ cursor,
                                                  int2* __restrict__ pack, int nnz) {
    const int f      = blockIdx.x & 7;
    const int slice  = blockIdx.x >> 3;
    const int nslice = SCAT_BLOCKS / 8;
    const int per    = (nnz + nslice - 1) / nslice;
    const int begin  = slice * per;
    const int end    = min(begin + per, nnz);
    for (int i = begin + threadIdx.x; i < end; i += 256) {
        int c = cols[i];
        if ((c >> CSHIFT) == f) {
            int r   = rows[i];
            int pos = atomicAdd(&cursor[mk_key(r, c)], 1);
            pack[pos] = make_int2(c, __float_as_int(values[i]));
        }
    }
}

// ---------------- K5: chunk-phased gather-accumulate (R3 structure) ----------------
// Statistical lockstep: 1024 equal-work co-resident blocks, ~32 items per
// wave per phase; blockIdx&7 staggers starting chunk per XCD so each XCD's
// L2 holds one ~2 MB dense slice at a time. No intra-block barrier.
__global__ __launch_bounds__(256, 4) void k_spmm(const float4* __restrict__ in4,
                                                 const int2* __restrict__ pack,
                                                 const int* __restrict__ bstart,
                                                 const float4* __restrict__ dense4,
                                                 float4* __restrict__ out4) {
    const int wave = threadIdx.x >> 6;
    const int lane = threadIdx.x & 63;
    const int rb   = blockIdx.x * RPB + wave * RPW;   // rows rb..rb+3
    const int ph0  = blockIdx.x & 7;

    float4 acc[RPW];
#pragma unroll
    for (int r = 0; r < RPW; ++r) acc[r] = make_float4(0.f, 0.f, 0.f, 0.f);

    for (int p = 0; p < CHUNKS; ++p) {
        const int c    = (ph0 + p) & 7;
        const int base = c * MROWS + rb;
#pragma unroll
        for (int r = 0; r < RPW; ++r) {
            int s = bstart[base + r];
            int e = bstart[base + r + 1];
            s = __builtin_amdgcn_readfirstlane(s);
            e = __builtin_amdgcn_readfirstlane(e);
            int i = s;
            for (; i + 4 <= e; i += 4) {
                int2 q0 = pack[i + 0], q1 = pack[i + 1];
                int2 q2 = pack[i + 2], q3 = pack[i + 3];
                float4 d0 = dense4[q0.x * NV4 + lane];
                float4 d1 = dense4[q1.x * NV4 + lane];
                float4 d2 = dense4[q2.x * NV4 + lane];
                float4 d3 = dense4[q3.x * NV4 + lane];
                float v0 = __int_as_float(q0.y), v1 = __int_as_float(q1.y);
                float v2 = __int_as_float(q2.y), v3 = __int_as_float(q3.y);
                acc[r].x += v0 * d0.x; acc[r].y += v0 * d0.y;
                acc[r].z += v0 * d0.z; acc[r].w += v0 * d0.w;
                acc[r].x += v1 * d1.x; acc[r].y += v1 * d1.y;
                acc[r].z += v1 * d1.z; acc[r].w += v1 * d1.w;
                acc[r].x += v2 * d2.x; acc[r].y += v2 * d2.y;
                acc[r].z += v2 * d2.z; acc[r].w += v2 * d2.w;
                acc[r].x += v3 * d3.x; acc[r].y += v3 * d3.y;
                acc[r].z += v3 * d3.z; acc[r].w += v3 * d3.w;
            }
            for (; i < e; ++i) {
                int2 q   = pack[i];
                float4 d = dense4[q.x * NV4 + lane];
                float v  = __int_as_float(q.y);
                acc[r].x += v * d.x; acc[r].y += v * d.y;
                acc[r].z += v * d.z; acc[r].w += v * d.w;
            }
        }
    }

#pragma unroll
    for (int r = 0; r < RPW; ++r) {
        const int o = (rb + r) * NV4 + lane;
        float4 iv = in4[o];
        out4[o] = make_float4(iv.x + acc[r].x, iv.y + acc[r].y,
                              iv.z + acc[r].z, iv.w + acc[r].w);
    }
}

// ---------------- Last-resort fallback (tiny ws): copy + atomic scatter ----------------
__global__ void k_copy4(const float4* __restrict__ in4, float4* __restrict__ out4, int n4) {
    int t = blockIdx.x * blockDim.x + threadIdx.x;
    if (t < n4) out4[t] = in4[t];
}

__global__ void k_atomic(const float* __restrict__ values, const int* __restrict__ rows,
                         const int* __restrict__ cols, const float4* __restrict__ dense4,
                         float* __restrict__ out, int nnz) {
    long long t = (long long)blockIdx.x * blockDim.x + threadIdx.x;
    long long total = (long long)nnz * 64;
    if (t >= total) return;
    int i   = (int)(t >> 6);
    int seg = (int)(t & 63);
    float v  = values[i];
    float4 d = dense4[cols[i] * NV4 + seg];
    float* o = out + (size_t)rows[i] * NCOLS + seg * 4;
    atomicAdd(o + 0, v * d.x);
    atomicAdd(o + 1, v * d.y);
    atomicAdd(o + 2, v * d.z);
    atomicAdd(o + 3, v * d.w);
}

extern "C" void kernel_launch(void* const* d_in, const int* in_sizes, int n_in,
                              void* d_out, int out_size, void* d_ws, size_t ws_size,
                              hipStream_t stream) {
    const float* input_mat = (const float*)d_in[0];
    const float* values    = (const float*)d_in[1];
    const int*   rows      = (const int*)d_in[2];
    const int*   cols      = (const int*)d_in[3];
    const float* dense     = (const float*)d_in[4];
    float*       out       = (float*)d_out;

    const int nnz = in_sizes[1];

    // ws layout: cursor[NB] | bstart[NB+1] | bsum[512] | bpre[513] | pack[nnz] | stage[nnz]
    const size_t off_cursor = 0;
    const size_t off_bs     = (size_t)NB * 4;
    const size_t off_bsum   = off_bs + ((size_t)NB + 1) * 4;
    const size_t off_bpre   = off_bsum + 512 * 4;
    size_t off_pack         = off_bpre + 513 * 4;
    off_pack                = (off_pack + 255) & ~(size_t)255;
    const size_t off_stage  = off_pack + (size_t)nnz * 8;
    const size_t need_full  = off_stage + (size_t)nnz * 8;
    const size_t need_mid   = off_stage;          // without stage

    char* ws = (char*)d_ws;

    if (ws_size >= need_mid) {
        int*  cursor = (int*)(ws + off_cursor);
        int*  bstart = (int*)(ws + off_bs);
        int*  bsum   = (int*)(ws + off_bsum);
        int*  bpre   = (int*)(ws + off_bpre);
        int2* pack   = (int2*)(ws + off_pack);
        int2* stage  = (int2*)(ws + off_stage);
        const bool full = (ws_size >= need_full);

        hipMemsetAsync(cursor, 0, (size_t)NB * 4, stream);
        const int quads = (nnz + 3) / 4;
        if (full) {
            k_fuse<<<(quads + 255) / 256, 256, 0, stream>>>(rows, cols, values,
                                                            cursor, stage, nnz);
        } else {
            // hist only (no stage): reuse fuse with stage=pack then overwrite later
            // -> simpler: raw hist via fuse is not possible; do atomics inline
            k_fuse<<<(quads + 255) / 256, 256, 0, stream>>>(rows, cols, values,
                                                            cursor, pack, nnz);
        }
        k_scan1<<<NB / 256, 256, 0, stream>>>(cursor, bsum);
        k_scan2<<<1, 512, 0, stream>>>(bsum, bpre);
        k_scan3<<<NB / 256, 256, 0, stream>>>(cursor, bpre, bstart, cursor);
        if (full) {
            k_scat<<<SCAT_BLOCKS, 256, 0, stream>>>(stage, cursor, pack, nnz);
        } else {
            k_scat_raw<<<SCAT_BLOCKS, 256, 0, stream>>>(values, rows, cols,
                                                        cursor, pack, nnz);
        }
        k_spmm<<<SPMM_BLOCKS, 256, 0, stream>>>((const float4*)input_mat, pack, bstart,
                                                (const float4*)dense, (float4*)out);
    } else {
        // last-resort: atomic scatter (slow but needs no scratch)
        const int n4 = MROWS * NV4;
        k_copy4<<<(n4 + 255) / 256, 256, 0, stream>>>((const float4*)input_mat,
                                                      (float4*)out, n4);
        long long total = (long long)nnz * 64;
        int blocks = (int)((total + 255) / 256);
        k_atomic<<<blocks, 256, 0, stream>>>(values, rows, cols, (const float4*)dense,
                                             out, nnz);
    }
}

// Round 9
// 163.330 us; speedup vs baseline: 1.1360x; 1.0181x over previous
//
#include <hip/hip_runtime.h>

#define MROWS   16384
#define NCOLS   256
#define NV4     (NCOLS / 4)        // 64 float4 per row
#define CHUNKS  8                  // column chunks: col>>11 -> 2048 rows = 2 MB each
#define CSHIFT  11
#define NB      (MROWS * CHUNKS)   // 131072 buckets

__device__ __forceinline__ int mk_key(int r, int c) {
    return ((c >> CSHIFT) << 14) | r;
}

// pad each bucket count to a multiple of 4 -> spmm has no tail loop
__device__ __forceinline__ int pad4(int c) { return (c + 3) & ~3; }

#define SPMM_BLOCKS 1024
#define RPB 16                                 // rows per block
#define RPW 4                                  // rows per wave

#define SCAT_BLOCKS 2048

// ---------------- K1: fused stage-write + histogram ----------------
__global__ __launch_bounds__(256) void k_fuse(const int* __restrict__ rows,
                                              const int* __restrict__ cols,
                                              const float* __restrict__ vals,
                                              int* __restrict__ cnt,
                                              int2* __restrict__ stage, int nnz) {
    int t = blockIdx.x * blockDim.x + threadIdx.x;
    int i = t * 4;
    if (i + 3 < nnz) {
        int4   r = *(const int4*)(rows + i);
        int4   c = *(const int4*)(cols + i);
        float4 v = *(const float4*)(vals + i);
        stage[i + 0] = make_int2((r.x << 14) | c.x, __float_as_int(v.x));
        stage[i + 1] = make_int2((r.y << 14) | c.y, __float_as_int(v.y));
        stage[i + 2] = make_int2((r.z << 14) | c.z, __float_as_int(v.z));
        stage[i + 3] = make_int2((r.w << 14) | c.w, __float_as_int(v.w));
        atomicAdd(&cnt[mk_key(r.x, c.x)], 1);
        atomicAdd(&cnt[mk_key(r.y, c.y)], 1);
        atomicAdd(&cnt[mk_key(r.z, c.z)], 1);
        atomicAdd(&cnt[mk_key(r.w, c.w)], 1);
    } else {
        for (int j = i; j < nnz; ++j) {
            int r = rows[j], c = cols[j];
            stage[j] = make_int2((r << 14) | c, __float_as_int(vals[j]));
            atomicAdd(&cnt[mk_key(r, c)], 1);
        }
    }
}

// ---------------- scan stage 1: per-block sums of PADDED counts ----------------
__global__ __launch_bounds__(256) void k_scan1(const int* __restrict__ cnt,
                                               int* __restrict__ bsum) {
    __shared__ int sm[256];
    const int t = threadIdx.x;
    sm[t] = pad4(cnt[blockIdx.x * 256 + t]);
    __syncthreads();
    for (int off = 128; off > 0; off >>= 1) {
        if (t < off) sm[t] += sm[t + off];
        __syncthreads();
    }
    if (t == 0) bsum[blockIdx.x] = sm[0];
}

// ---------------- scan stage 2: 1 block scans the 512 block sums ----------------
__global__ __launch_bounds__(512) void k_scan2(const int* __restrict__ bsum,
                                               int* __restrict__ bpre) {
    __shared__ int sm[512];
    const int t = threadIdx.x;
    int v = bsum[t];
    sm[t] = v;
    __syncthreads();
    for (int off = 1; off < 512; off <<= 1) {
        int u = 0;
        if (t >= off) u = sm[t - off];
        __syncthreads();
        if (t >= off) sm[t] += u;
        __syncthreads();
    }
    bpre[t] = sm[t] - v;                 // exclusive
    if (t == 511) bpre[512] = sm[511];   // total (padded)
}

// ---------------- scan stage 3: final exclusive prefix of PADDED counts ----------------
__global__ __launch_bounds__(256) void k_scan3(const int* __restrict__ cnt_in,
                                               const int* __restrict__ bpre,
                                               int* __restrict__ bstart,
                                               int* __restrict__ cursor) {
    __shared__ int sm[256];
    const int t = threadIdx.x;
    const int g = blockIdx.x * 256 + t;
    int v = pad4(cnt_in[g]);
    sm[t] = v;
    __syncthreads();
    for (int off = 1; off < 256; off <<= 1) {
        int u = 0;
        if (t >= off) u = sm[t - off];
        __syncthreads();
        if (t >= off) sm[t] += u;
        __syncthreads();
    }
    int excl = sm[t] - v + bpre[blockIdx.x];
    bstart[g] = excl;
    cursor[g] = excl;
    if (blockIdx.x == gridDim.x - 1 && t == 255) bstart[NB] = bpre[512];
}

// ---------------- K4: XCD-filtered scatter -> 4B pack (col<<16 | fp16 val) ----------------
__global__ __launch_bounds__(256) void k_scat(const int2* __restrict__ stage,
                                              int* __restrict__ cursor,
                                              unsigned* __restrict__ pack, int nnz) {
    const int f      = blockIdx.x & 7;          // chunk filter
    const int slice  = blockIdx.x >> 3;
    const int nslice = SCAT_BLOCKS / 8;
    const int per    = (nnz + nslice - 1) / nslice;
    const int begin  = slice * per;
    const int end    = min(begin + per, nnz);
    for (int i = begin + threadIdx.x; i < end; i += 256) {
        int2 it  = stage[i];
        int  col = it.x & 16383;
        if ((col >> CSHIFT) == f) {
            int row = it.x >> 14;
            int pos = atomicAdd(&cursor[(f << 14) | row], 1);
            _Float16 h = (_Float16)__int_as_float(it.y);
            pack[pos] = ((unsigned)col << 16) |
                        (unsigned)__builtin_bit_cast(unsigned short, h);
        }
    }
}

// ---------------- K4b: raw-array scatter (mid-tier ws fallback) ----------------
__global__ __launch_bounds__(256) void k_scat_raw(const float* __restrict__ values,
                                                  const int* __restrict__ rows,
                                                  const int* __restrict__ cols,
                                                  int* __restrict__ cursor,
                                                  unsigned* __restrict__ pack, int nnz) {
    const int f      = blockIdx.x & 7;
    const int slice  = blockIdx.x >> 3;
    const int nslice = SCAT_BLOCKS / 8;
    const int per    = (nnz + nslice - 1) / nslice;
    const int begin  = slice * per;
    const int end    = min(begin + per, nnz);
    for (int i = begin + threadIdx.x; i < end; i += 256) {
        int c = cols[i];
        if ((c >> CSHIFT) == f) {
            int r   = rows[i];
            int pos = atomicAdd(&cursor[mk_key(r, c)], 1);
            _Float16 h = (_Float16)values[i];
            pack[pos] = ((unsigned)c << 16) |
                        (unsigned)__builtin_bit_cast(unsigned short, h);
        }
    }
}

// ---------------- K5: chunk-phased gather-accumulate, padded segments ----------------
// Segments are multiples of 4 (pads are zero words -> col 0, val 0, harmless,
// L1-hot). No tail loop; quad metadata is one int4 load; unroll-2 quads
// -> 8 gathers in flight.
__global__ __launch_bounds__(256, 4) void k_spmm(const float4* __restrict__ in4,
                                                 const unsigned* __restrict__ pack,
                                                 const int* __restrict__ bstart,
                                                 const float4* __restrict__ dense4,
                                                 float4* __restrict__ out4) {
    const int wave = threadIdx.x >> 6;
    const int lane = threadIdx.x & 63;
    const int rb   = blockIdx.x * RPB + wave * RPW;   // rows rb..rb+3
    const int ph0  = blockIdx.x & 7;

    float4 acc[RPW];
#pragma unroll
    for (int r = 0; r < RPW; ++r) acc[r] = make_float4(0.f, 0.f, 0.f, 0.f);

    for (int p = 0; p < CHUNKS; ++p) {
        const int c    = (ph0 + p) & 7;
        const int base = c * MROWS + rb;
#pragma unroll
        for (int r = 0; r < RPW; ++r) {
            int s = bstart[base + r];
            int e = bstart[base + r + 1];
            s = __builtin_amdgcn_readfirstlane(s);
            e = __builtin_amdgcn_readfirstlane(e);
            int i = s;
            for (; i + 8 <= e; i += 8) {
                int4 qa = *(const int4*)(pack + i);
                int4 qb = *(const int4*)(pack + i + 4);
                float4 d0 = dense4[((unsigned)qa.x >> 16) * NV4 + lane];
                float4 d1 = dense4[((unsigned)qa.y >> 16) * NV4 + lane];
                float4 d2 = dense4[((unsigned)qa.z >> 16) * NV4 + lane];
                float4 d3 = dense4[((unsigned)qa.w >> 16) * NV4 + lane];
                float4 d4 = dense4[((unsigned)qb.x >> 16) * NV4 + lane];
                float4 d5 = dense4[((unsigned)qb.y >> 16) * NV4 + lane];
                float4 d6 = dense4[((unsigned)qb.z >> 16) * NV4 + lane];
                float4 d7 = dense4[((unsigned)qb.w >> 16) * NV4 + lane];
                float v0 = (float)__builtin_bit_cast(_Float16, (unsigned short)(qa.x & 0xFFFF));
                float v1 = (float)__builtin_bit_cast(_Float16, (unsigned short)(qa.y & 0xFFFF));
                float v2 = (float)__builtin_bit_cast(_Float16, (unsigned short)(qa.z & 0xFFFF));
                float v3 = (float)__builtin_bit_cast(_Float16, (unsigned short)(qa.w & 0xFFFF));
                float v4 = (float)__builtin_bit_cast(_Float16, (unsigned short)(qb.x & 0xFFFF));
                float v5 = (float)__builtin_bit_cast(_Float16, (unsigned short)(qb.y & 0xFFFF));
                float v6 = (float)__builtin_bit_cast(_Float16, (unsigned short)(qb.z & 0xFFFF));
                float v7 = (float)__builtin_bit_cast(_Float16, (unsigned short)(qb.w & 0xFFFF));
                acc[r].x += v0 * d0.x; acc[r].y += v0 * d0.y;
                acc[r].z += v0 * d0.z; acc[r].w += v0 * d0.w;
                acc[r].x += v1 * d1.x; acc[r].y += v1 * d1.y;
                acc[r].z += v1 * d1.z; acc[r].w += v1 * d1.w;
                acc[r].x += v2 * d2.x; acc[r].y += v2 * d2.y;
                acc[r].z += v2 * d2.z; acc[r].w += v2 * d2.w;
                acc[r].x += v3 * d3.x; acc[r].y += v3 * d3.y;
                acc[r].z += v3 * d3.z; acc[r].w += v3 * d3.w;
                acc[r].x += v4 * d4.x; acc[r].y += v4 * d4.y;
                acc[r].z += v4 * d4.z; acc[r].w += v4 * d4.w;
                acc[r].x += v5 * d5.x; acc[r].y += v5 * d5.y;
                acc[r].z += v5 * d5.z; acc[r].w += v5 * d5.w;
                acc[r].x += v6 * d6.x; acc[r].y += v6 * d6.y;
                acc[r].z += v6 * d6.z; acc[r].w += v6 * d6.w;
                acc[r].x += v7 * d7.x; acc[r].y += v7 * d7.y;
                acc[r].z += v7 * d7.z; acc[r].w += v7 * d7.w;
            }
            if (i < e) {   // exactly one remaining quad (segments are %4)
                int4 qa = *(const int4*)(pack + i);
                float4 d0 = dense4[((unsigned)qa.x >> 16) * NV4 + lane];
                float4 d1 = dense4[((unsigned)qa.y >> 16) * NV4 + lane];
                float4 d2 = dense4[((unsigned)qa.z >> 16) * NV4 + lane];
                float4 d3 = dense4[((unsigned)qa.w >> 16) * NV4 + lane];
                float v0 = (float)__builtin_bit_cast(_Float16, (unsigned short)(qa.x & 0xFFFF));
                float v1 = (float)__builtin_bit_cast(_Float16, (unsigned short)(qa.y & 0xFFFF));
                float v2 = (float)__builtin_bit_cast(_Float16, (unsigned short)(qa.z & 0xFFFF));
                float v3 = (float)__builtin_bit_cast(_Float16, (unsigned short)(qa.w & 0xFFFF));
                acc[r].x += v0 * d0.x; acc[r].y += v0 * d0.y;
                acc[r].z += v0 * d0.z; acc[r].w += v0 * d0.w;
                acc[r].x += v1 * d1.x; acc[r].y += v1 * d1.y;
                acc[r].z += v1 * d1.z; acc[r].w += v1 * d1.w;
                acc[r].x += v2 * d2.x; acc[r].y += v2 * d2.y;
                acc[r].z += v2 * d2.z; acc[r].w += v2 * d2.w;
                acc[r].x += v3 * d3.x; acc[r].y += v3 * d3.y;
                acc[r].z += v3 * d3.z; acc[r].w += v3 * d3.w;
            }
        }
    }

#pragma unroll
    for (int r = 0; r < RPW; ++r) {
        const int o = (rb + r) * NV4 + lane;
        float4 iv = in4[o];
        out4[o] = make_float4(iv.x + acc[r].x, iv.y + acc[r].y,
                              iv.z + acc[r].z, iv.w + acc[r].w);
    }
}

// ---------------- Last-resort fallback (tiny ws): copy + atomic scatter ----------------
__global__ void k_copy4(const float4* __restrict__ in4, float4* __restrict__ out4, int n4) {
    int t = blockIdx.x * blockDim.x + threadIdx.x;
    if (t < n4) out4[t] = in4[t];
}

__global__ void k_atomic(const float* __restrict__ values, const int* __restrict__ rows,
                         const int* __restrict__ cols, const float4* __restrict__ dense4,
                         float* __restrict__ out, int nnz) {
    long long t = (long long)blockIdx.x * blockDim.x + threadIdx.x;
    long long total = (long long)nnz * 64;
    if (t >= total) return;
    int i   = (int)(t >> 6);
    int seg = (int)(t & 63);
    float v  = values[i];
    float4 d = dense4[cols[i] * NV4 + seg];
    float* o = out + (size_t)rows[i] * NCOLS + seg * 4;
    atomicAdd(o + 0, v * d.x);
    atomicAdd(o + 1, v * d.y);
    atomicAdd(o + 2, v * d.z);
    atomicAdd(o + 3, v * d.w);
}

extern "C" void kernel_launch(void* const* d_in, const int* in_sizes, int n_in,
                              void* d_out, int out_size, void* d_ws, size_t ws_size,
                              hipStream_t stream) {
    const float* input_mat = (const float*)d_in[0];
    const float* values    = (const float*)d_in[1];
    const int*   rows      = (const int*)d_in[2];
    const int*   cols      = (const int*)d_in[3];
    const float* dense     = (const float*)d_in[4];
    float*       out       = (float*)d_out;

    const int nnz = in_sizes[1];

    // pack capacity with padding: nnz + 3 per bucket (upper bound)
    const size_t pack_cap  = (size_t)nnz + 3 * (size_t)NB;

    // ws layout: cursor[NB] | bstart[NB+1] | bsum[512] | bpre[513] | pack[cap] u32 | stage[nnz] int2
    const size_t off_cursor = 0;
    const size_t off_bs     = (size_t)NB * 4;
    const size_t off_bsum   = off_bs + ((size_t)NB + 1) * 4;
    const size_t off_bpre   = off_bsum + 512 * 4;
    size_t off_pack         = off_bpre + 513 * 4;
    off_pack                = (off_pack + 255) & ~(size_t)255;
    size_t off_stage        = off_pack + pack_cap * 4;
    off_stage               = (off_stage + 255) & ~(size_t)255;
    const size_t need_full  = off_stage + (size_t)nnz * 8;
    const size_t need_mid   = off_stage;

    char* ws = (char*)d_ws;

    if (ws_size >= need_mid) {
        int*      cursor = (int*)(ws + off_cursor);
        int*      bstart = (int*)(ws + off_bs);
        int*      bsum   = (int*)(ws + off_bsum);
        int*      bpre   = (int*)(ws + off_bpre);
        unsigned* pack   = (unsigned*)(ws + off_pack);
        int2*     stage  = (int2*)(ws + off_stage);
        const bool full  = (ws_size >= need_full);

        hipMemsetAsync(cursor, 0, (size_t)NB * 4, stream);
        hipMemsetAsync(pack, 0, pack_cap * 4, stream);   // pad entries read as 0

        const int quads = (nnz + 3) / 4;
        if (full) {
            k_fuse<<<(quads + 255) / 256, 256, 0, stream>>>(rows, cols, values,
                                                            cursor, stage, nnz);
        } else {
            // mid tier: no stage buffer; hist via fuse writing throwaway into
            // pack region is unsafe (pack must stay zero) -> plain hist loop
            k_fuse<<<(quads + 255) / 256, 256, 0, stream>>>(rows, cols, values,
                                                            cursor,
                                                            (int2*)pack, nnz);
            // pack will be re-zeroed below before scatter
        }
        k_scan1<<<NB / 256, 256, 0, stream>>>(cursor, bsum);
        k_scan2<<<1, 512, 0, stream>>>(bsum, bpre);
        k_scan3<<<NB / 256, 256, 0, stream>>>(cursor, bpre, bstart, cursor);
        if (full) {
            k_scat<<<SCAT_BLOCKS, 256, 0, stream>>>(stage, cursor, pack, nnz);
        } else {
            hipMemsetAsync(pack, 0, pack_cap * 4, stream);  // re-zero (was hist scratch)
            k_scat_raw<<<SCAT_BLOCKS, 256, 0, stream>>>(values, rows, cols,
                                                        cursor, pack, nnz);
        }
        k_spmm<<<SPMM_BLOCKS, 256, 0, stream>>>((const float4*)input_mat, pack, bstart,
                                                (const float4*)dense, (float4*)out);
    } else {
        // last-resort: atomic scatter (slow but needs no scratch)
        const int n4 = MROWS * NV4;
        k_copy4<<<(n4 + 255) / 256, 256, 0, stream>>>((const float4*)input_mat,
                                                      (float4*)out, n4);
        long long total = (long long)nnz * 64;
        int blocks = (int)((total + 255) / 256);
        k_atomic<<<blocks, 256, 0, stream>>>(values, rows, cols, (const float4*)dense,
                                             out, nnz);
    }
}